// Round 12
// baseline (317.388 us; speedup 1.0000x reference)
//
#include <hip/hip_runtime.h>

#define SLOPE 0.01f
#define EPSV  1e-5f
#define BB    64
#define NN    500
#define TT    50
#define E_N   16000
#define FF    43
#define PP    500
#define HH    128
#define XSTRIDE 48

typedef const float* fp;

__device__ __forceinline__ float lrelu(float x){ return x >= 0.f ? x : SLOPE * x; }
__device__ __forceinline__ float bnap(float x, fp bnp, int c, int C){
  float g  = bnp[c], b_ = bnp[C + c];
  float m  = bnp[2*C + c], v = bnp[3*C + c];
  float s = g * rsqrtf(v + EPSV);
  return x * s + (b_ - m * s);
}

// ============ prep chain (unchanged) ============
__global__ __launch_bounds__(1024) void k_prep8(
    fp sc2w, fp mc2w, fp gwroot, fp gwrel,
    float* __restrict__ wT_s2, float* __restrict__ wT_m2, float* __restrict__ wTg,
    int* __restrict__ cnt, int* __restrict__ ideg)
{
  int tid = threadIdx.x, blk = blockIdx.x;
  if (blk == 0){
    for (int i = tid; i < 2880; i += 1024){ int o = i/144, x = i%144; wT_s2[x*20+o] = sc2w[i]; }
  } else if (blk == 1){
    for (int i = tid; i < 1800; i += 1024){ int o = i/90,  x = i%90;  wT_m2[x*20+o] = mc2w[i]; }
  } else if (blk < 6){
    for (int i = (blk-2)*1024 + tid; i < 9245; i += 4096){
      int f5 = i/43, g = i%43;
      wTg[i] = (f5 < 43) ? gwroot[f5*43+g] : gwrel[(f5-43)*43+g];
    }
  } else if (blk == 6){
    for (int i = tid; i < 512;  i += 1024) cnt[i] = 0;
    for (int i = tid; i < 2048; i += 1024) ideg[i] = 0;
  } else {
    for (int i = 9245 + tid; i < 9312; i += 1024) wTg[i] = 0.f;
  }
}

__global__ __launch_bounds__(256) void k_count8(
    const int* __restrict__ ei, const int* __restrict__ et,
    int* __restrict__ cnt, int* __restrict__ ideg)
{
  int i = blockIdx.x*256 + threadIdx.x;
  if (i < E_N){
    int d = ei[E_N+i], r = et[i];
    atomicAdd(&cnt[d], 1);
    atomicAdd(&ideg[r*NN+d], 1);
  }
}

__global__ __launch_bounds__(512) void k_scan8(
    const int* __restrict__ cnt, const int* __restrict__ ideg,
    int* __restrict__ begr, int* __restrict__ cursor4, float* __restrict__ inv_deg)
{
  __shared__ int sc[512];
  int tid = threadIdx.x;
  sc[tid] = cnt[tid];
  __syncthreads();
  for (int off = 1; off < 512; off <<= 1){
    int v = (tid >= off) ? sc[tid-off] : 0;
    __syncthreads();
    sc[tid] += v;
    __syncthreads();
  }
  if (tid < NN){
    int o  = tid ? sc[tid-1] : 0;
    int c1 = o  + ideg[tid];
    int c2 = c1 + ideg[NN + tid];
    int c3 = c2 + ideg[2*NN + tid];
    begr[tid*4+0] = o;  begr[tid*4+1] = c1;
    begr[tid*4+2] = c2; begr[tid*4+3] = c3;
    cursor4[tid*4+0] = o;  cursor4[tid*4+1] = c1;
    cursor4[tid*4+2] = c2; cursor4[tid*4+3] = c3;
    #pragma unroll
    for (int r = 0; r < 4; r++)
      inv_deg[r*NN+tid] = 1.f / fmaxf((float)ideg[r*NN+tid], 1.f);
  }
  if (tid == 0) begr[2000] = E_N;
}

__global__ __launch_bounds__(256) void k_fill8(
    const int* __restrict__ ei, const int* __restrict__ et,
    int* __restrict__ cursor4, int* __restrict__ e_s)
{
  int i = blockIdx.x*256 + threadIdx.x;
  if (i < E_N){
    int s = ei[i], d = ei[E_N+i], r = et[i];
    int pos = atomicAdd(&cursor4[d*4+r], 1);
    e_s[pos] = s;
  }
}

// ============ NEW: obs transpose  obs[b][c][n][t] -> obsT[(b*3+c)*50+t][n] ====
__global__ __launch_bounds__(256) void k_transp(
    fp obs, float* __restrict__ obsT)
{
  __shared__ float tile[64][51];
  int bx = blockIdx.x;          // 64*3*8
  int b = bx / 24, rem = bx % 24;
  int c = rem / 8, nt = rem % 8;
  int n0 = nt * 64;
  int span = (NN - n0 < 64) ? (NN - n0) : 64;
  int tid = threadIdx.x;
  const float* src = obs + ((size_t)(b*3 + c)*NN + n0)*TT;
  for (int idx = tid; idx < span*50; idx += 256)
    tile[idx/50][idx%50] = src[idx];
  __syncthreads();
  float* dst = obsT + (size_t)(b*3 + c)*50*500 + n0;
  for (int idx = tid; idx < 50*64; idx += 256){
    int t = idx >> 6, q = idx & 63;
    if (q < span) dst[(size_t)t*500 + q] = tile[q][t];
  }
}

// ============ temporal v12: LDS-free compute, register streaming ============
// 512 blocks (b, n-tile 64) x 512 thr (8 waves). Waves 0-4: m-branch (6 t each);
// waves 5-7: s-branch (16 t each) + l-max slice. Only LDS: partial buffer.
__global__ __launch_bounds__(512, 4) void k_tempo12(
    const float* __restrict__ obsT,
    fp sc1w, fp sc1b, fp sbn1, fp sc2b, fp sbn2,
    fp mc1w, fp mc1b, fp mbn1, fp mc2b, fp mbn2,
    const float* __restrict__ wT_s2, const float* __restrict__ wT_m2,
    float* __restrict__ xbuf)
{
  __shared__ float pbuf[8][64][23];
  int tid = threadIdx.x;
  int w = __builtin_amdgcn_readfirstlane(tid >> 6);   // SGPR wave id
  int lane = tid & 63;
  int b  = blockIdx.x >> 3;
  int n0 = (blockIdx.x & 7) << 6;
  int span = (NN - n0 < 64) ? (NN - n0) : 64;
  int nn = n0 + lane; if (nn > NN-1) nn = NN-1;       // clamp (dup loads ok)
  const float* oT = obsT + (size_t)b*3*50*500;        // + (ci*50+t)*500 + nn

  if (w < 5){
    // ---- m-branch: t' in [w*6, w*6+6); window width 26 per channel ----
    int t0 = w * 6;
    float ov[3][26];
    #pragma unroll
    for (int ci = 0; ci < 3; ci++)
      #pragma unroll
      for (int j = 0; j < 26; j++)
        ov[ci][j] = oT[(size_t)(ci*50 + t0 + j)*500 + nn];
    float sc1[3], sh1[3];
    #pragma unroll
    for (int ci = 0; ci < 3; ci++){
      float s = mbn1[ci] * rsqrtf(mbn1[9+ci] + EPSV);
      sc1[ci] = s; sh1[ci] = mbn1[3+ci] - mbn1[6+ci]*s;
    }
    float acc[20];
    #pragma unroll
    for (int o = 0; o < 20; o++) acc[o] = 0.f;
    #pragma unroll
    for (int i = 0; i < 6; i++){
      int tt = t0 + i;                                // SGPR
      float mv[3];
      #pragma unroll
      for (int co = 0; co < 3; co++) mv[co] = mc1b[co];
      #pragma unroll
      for (int ci = 0; ci < 3; ci++)
        #pragma unroll
        for (int k = 0; k < 21; k++){
          float v = ov[ci][i + k];
          #pragma unroll
          for (int co = 0; co < 3; co++) mv[co] += v * mc1w[co*63 + ci*21 + k];
        }
      #pragma unroll
      for (int co = 0; co < 3; co++){
        float z = lrelu(mv[co]*sc1[co] + sh1[co]);
        const float* wp = wT_m2 + (co*30 + tt)*20;    // SGPR -> s_load, no ds contention
        #pragma unroll
        for (int o = 0; o < 20; o++) acc[o] += z * wp[o];
      }
    }
    #pragma unroll
    for (int o = 0; o < 20; o++) pbuf[w][lane][o] = acc[o];
  } else {
    // ---- s-branch: t' in [(w-5)*16, +16); window 18 ----
    int ws_ = w - 5;
    int t0 = ws_ * 16;
    float ovs[3][18];
    #pragma unroll
    for (int ci = 0; ci < 3; ci++)
      #pragma unroll
      for (int j = 0; j < 18; j++)
        ovs[ci][j] = oT[(size_t)(ci*50 + t0 + j)*500 + nn];
    float sc1[3], sh1[3];
    #pragma unroll
    for (int ci = 0; ci < 3; ci++){
      float s = sbn1[ci] * rsqrtf(sbn1[9+ci] + EPSV);
      sc1[ci] = s; sh1[ci] = sbn1[3+ci] - sbn1[6+ci]*s;
    }
    float acc[20];
    #pragma unroll
    for (int o = 0; o < 20; o++) acc[o] = 0.f;
    #pragma unroll
    for (int i = 0; i < 16; i++){
      int tt = t0 + i;
      float sv[3];
      #pragma unroll
      for (int co = 0; co < 3; co++) sv[co] = sc1b[co];
      #pragma unroll
      for (int ci = 0; ci < 3; ci++)
        #pragma unroll
        for (int k = 0; k < 3; k++){
          float v = ovs[ci][i + k];
          #pragma unroll
          for (int co = 0; co < 3; co++) sv[co] += v * sc1w[co*9 + ci*3 + k];
        }
      #pragma unroll
      for (int co = 0; co < 3; co++){
        float z = lrelu(sv[co]*sc1[co] + sh1[co]);
        const float* wp = wT_s2 + (co*48 + tt)*20;
        #pragma unroll
        for (int o = 0; o < 20; o++) acc[o] += z * wp[o];
      }
    }
    #pragma unroll
    for (int o = 0; o < 20; o++) pbuf[w][lane][o] = acc[o];
    // ---- l-branch slice: max over t in [ws_*17, +17) (16 on last) ----
    int l0 = ws_ * 17;
    int ln = (50 - l0 < 17) ? (50 - l0) : 17;
    float mx[3] = {-1e30f, -1e30f, -1e30f};
    for (int j = 0; j < ln; j++){
      #pragma unroll
      for (int c = 0; c < 3; c++)
        mx[c] = fmaxf(mx[c], oT[(size_t)(c*50 + l0 + j)*500 + nn]);
    }
    #pragma unroll
    for (int c = 0; c < 3; c++) pbuf[w][lane][20 + c] = mx[c];
  }
  __syncthreads();

  size_t gx = (size_t)(b*NN + n0)*XSTRIDE;
  // m outputs (cols 20..39)
  for (int idx = tid; idx < 64*20; idx += 512){
    int n = idx / 20, o = idx % 20;
    if (n < span){
      float v = pbuf[0][n][o] + pbuf[1][n][o] + pbuf[2][n][o]
              + pbuf[3][n][o] + pbuf[4][n][o];
      xbuf[gx + (size_t)n*XSTRIDE + 20 + o] = lrelu(bnap(v + mc2b[o], mbn2, o, 20));
    }
  }
  // s outputs (cols 0..19)
  for (int idx = tid; idx < 64*20; idx += 512){
    int n = idx / 20, o = idx % 20;
    if (n < span){
      float v = pbuf[5][n][o] + pbuf[6][n][o] + pbuf[7][n][o];
      xbuf[gx + (size_t)n*XSTRIDE + o] = lrelu(bnap(v + sc2b[o], sbn2, o, 20));
    }
  }
  // l outputs (cols 40..42)
  for (int idx = tid; idx < 64*3; idx += 512){
    int n = idx / 3, c = idx % 3;
    if (n < span){
      float v = fmaxf(fmaxf(pbuf[5][n][20+c], pbuf[6][n][20+c]), pbuf[7][n][20+c]);
      xbuf[gx + (size_t)n*XSTRIDE + 40 + c] = lrelu(v);
    }
  }
}

// ============ graph (unchanged from r8) ============
__global__ __launch_bounds__(1024) void k_graph8(
    const float* __restrict__ xbuf, const float* __restrict__ wTg,
    fp gb, fp gbnp, const float* __restrict__ inv_deg,
    const int* __restrict__ begr, const int* __restrict__ e_s,
    float* __restrict__ gbuf)
{
  __shared__ float xin[64][219];
  int tid = threadIdx.x;
  int w = tid >> 6, lane = tid & 63;
  int g0 = blockIdx.x * 64;

  for (int q = 0; q < 4; q++){
    int nl = (w << 2) + q;
    int g = __builtin_amdgcn_readfirstlane(g0 + nl);
    int b = g / NN;
    int n = g - b * NN;
    int gb0 = b * NN;
    float xv = (lane < FF) ? xbuf[(size_t)g*XSTRIDE + lane] : 0.f;
    float ar[4];
    #pragma unroll
    for (int r = 0; r < 4; r++){
      int beg = __builtin_amdgcn_readfirstlane(begr[n*4 + r]);
      int end = __builtin_amdgcn_readfirstlane(begr[n*4 + r + 1]);
      float a = 0.f;
      for (int i = beg; i < end; i++){
        int s = e_s[i];
        a += (lane < FF) ? xbuf[(size_t)(gb0 + s)*XSTRIDE + lane] : 0.f;
      }
      ar[r] = a * inv_deg[r*NN + n];
    }
    if (lane < FF){
      xin[nl][lane]       = xv;
      xin[nl][ 43 + lane] = ar[0];
      xin[nl][ 86 + lane] = ar[1];
      xin[nl][129 + lane] = ar[2];
      xin[nl][172 + lane] = ar[3];
    }
  }
  __syncthreads();

  int c0 = __builtin_amdgcn_readfirstlane(w * 3);
  int g = g0 + lane;
  float acc[3];
  #pragma unroll
  for (int j = 0; j < 3; j++) acc[j] = (c0 + j < FF) ? gb[c0+j] : 0.f;
  for (int f = 0; f < 215; f++){
    float v = xin[lane][f];
    const float* wp = wTg + f*43 + c0;
    #pragma unroll
    for (int j = 0; j < 3; j++) acc[j] += v * wp[j];
  }
  #pragma unroll
  for (int j = 0; j < 3; j++){
    int c = c0 + j;
    if (c < FF)
      gbuf[(size_t)g*XSTRIDE + c] = lrelu(bnap(acc[j], gbnp, c, FF));
  }
}

// ============ head (unchanged from r9) ============
__global__ __launch_bounds__(256) void k_logits9(
    const float* __restrict__ xbuf, const float* __restrict__ gbuf,
    fp action, const int* __restrict__ nts, fp acw, fp acb,
    float* __restrict__ o_ws)
{
  __shared__ float feats[64][87];
  int b = blockIdx.x, tile = blockIdx.y;
  int tid = threadIdx.x;
  int p0 = tile * 64;
  int span = (PP - p0 < 64) ? (PP - p0) : 64;

  for (int j = tid; j < span*86; j += 256){
    int q = j / 86, c = j % 86;
    int np = nts[p0 + q];
    size_t row = (size_t)(b*NN + np)*XSTRIDE;
    feats[q][c] = (c < FF) ? xbuf[row + c] : gbuf[row + (c - FF)];
  }
  __syncthreads();
  if (tid < span){
    int p = p0 + tid;
    float acc = acb[0] + action[b*(PP+1) + 1 + p] * acw[0];
    #pragma unroll 2
    for (int c = 0; c < 86; c++) acc += feats[tid][c] * acw[1 + c];
    o_ws[b*(PP+1) + 1 + p] = acc;
  }
  if (tile == 0 && tid == 64) o_ws[b*(PP+1)] = 0.f;
}

__global__ __launch_bounds__(128) void k_fc1_9(
    const float* __restrict__ o_ws, fp aw1, float* __restrict__ part_ws)
{
  __shared__ float os[126];
  int b = blockIdx.x, chunk = blockIdx.y;
  int tid = threadIdx.x;
  int k0 = chunk * 125;
  int kn = (chunk == 3) ? 126 : 125;
  if (tid < kn) os[tid] = o_ws[b*(PP+1) + k0 + tid];
  __syncthreads();
  float acc = 0.f;
  for (int k = 0; k < kn; k++) acc += os[k] * aw1[(k0+k)*HH + tid];
  part_ws[(b*4 + chunk)*HH + tid] = acc;
}

__global__ __launch_bounds__(512) void k_fc23_9(
    const float* __restrict__ part_ws,
    fp ab1, fp aw2, fp ab2, fp aw3, fp ab3,
    float* __restrict__ out)
{
  int b = blockIdx.x;
  int tid = threadIdx.x;
  __shared__ float h1[HH];
  __shared__ float h2[HH];
  __shared__ float red[512];

  if (tid < HH){
    const float* pw = part_ws + b*4*HH;
    h1[tid] = fmaxf(ab1[tid] + pw[tid] + pw[HH+tid] + pw[2*HH+tid] + pw[3*HH+tid], 0.f);
  }
  __syncthreads();
  if (tid < HH){
    float acc = ab2[tid];
    #pragma unroll 4
    for (int k = 0; k < HH; k++) acc += h1[k] * aw2[k*HH + tid];
    h2[tid] = fmaxf(acc, 0.f);
  }
  __syncthreads();

  float val = -1e30f;
  if (tid <= PP){
    float acc = ab3[tid];
    #pragma unroll 4
    for (int k = 0; k < HH; k++) acc += h2[k] * aw3[k*(PP+1) + tid];
    val = acc;
  }
  red[tid] = val;
  __syncthreads();
  for (int s = 256; s > 0; s >>= 1){
    if (tid < s) red[tid] = fmaxf(red[tid], red[tid + s]);
    __syncthreads();
  }
  float mx = red[0];
  __syncthreads();
  float e = (tid <= PP) ? expf(val - mx) : 0.f;
  red[tid] = e;
  __syncthreads();
  for (int s = 256; s > 0; s >>= 1){
    if (tid < s) red[tid] += red[tid + s];
    __syncthreads();
  }
  float sum = red[0];
  if (tid <= PP) out[b*(PP+1) + tid] = e / sum;
}

extern "C" void kernel_launch(void* const* d_in, const int* in_sizes, int n_in,
                              void* d_out, int out_size, void* d_ws, size_t ws_size,
                              hipStream_t stream)
{
  fp obs    = (fp)d_in[0];
  fp action = (fp)d_in[1];
  const int* ei  = (const int*)d_in[2];
  const int* et  = (const int*)d_in[3];
  const int* nts = (const int*)d_in[4];
  fp sc1w=(fp)d_in[5],  sc1b=(fp)d_in[6],  sbn1=(fp)d_in[7];
  fp sc2w=(fp)d_in[8],  sc2b=(fp)d_in[9],  sbn2=(fp)d_in[10];
  fp mc1w=(fp)d_in[11], mc1b=(fp)d_in[12], mbn1=(fp)d_in[13];
  fp mc2w=(fp)d_in[14], mc2b=(fp)d_in[15], mbn2=(fp)d_in[16];
  fp gwroot=(fp)d_in[17], gwrel=(fp)d_in[18], gb=(fp)d_in[19], gbnp=(fp)d_in[20];
  fp acw=(fp)d_in[21], acb=(fp)d_in[22];
  fp aw1=(fp)d_in[23], ab1=(fp)d_in[24];
  fp aw2=(fp)d_in[25], ab2=(fp)d_in[26];
  fp aw3=(fp)d_in[27], ab3=(fp)d_in[28];

  float* xbuf   = (float*)d_ws;              // 1,536,000
  float* obsT   = xbuf + 1536000;            // 4,800,000 (dead after tempo)
  float* gbuf   = obsT;                      // aliases obsT (1,536,000 <= 4.8M)
  float* wT_s2  = obsT + 4800000;            // 2880
  float* wT_m2  = wT_s2 + 2880;              // 1800
  float* wTg    = wT_m2 + 1800;              // 9312
  float* invdeg = wTg + 9312;                // 2000
  int*   ip     = (int*)(invdeg + 2000);
  int* cnt     = ip;            // 512
  int* ideg    = ip + 512;      // 2048
  int* begr    = ip + 2560;     // 2001
  int* cursor4 = ip + 4561;     // 2000
  int* e_s     = ip + 6561;     // 16000
  float* o_ws    = (float*)(ip + 22561);     // 64*501
  float* part_ws = o_ws + 32064;             // 64*4*128

  float* out = (float*)d_out;

  hipLaunchKernelGGL(k_prep8, dim3(8), dim3(1024), 0, stream,
    sc2w, mc2w, gwroot, gwrel, wT_s2, wT_m2, wTg, cnt, ideg);
  hipLaunchKernelGGL(k_count8, dim3(63), dim3(256), 0, stream,
    ei, et, cnt, ideg);
  hipLaunchKernelGGL(k_scan8, dim3(1), dim3(512), 0, stream,
    cnt, ideg, begr, cursor4, invdeg);
  hipLaunchKernelGGL(k_fill8, dim3(63), dim3(256), 0, stream,
    ei, et, cursor4, e_s);
  hipLaunchKernelGGL(k_transp, dim3(64*3*8), dim3(256), 0, stream,
    obs, obsT);
  hipLaunchKernelGGL(k_tempo12, dim3(512), dim3(512), 0, stream,
    obsT, sc1w, sc1b, sbn1, sc2b, sbn2,
    mc1w, mc1b, mbn1, mc2b, mbn2, wT_s2, wT_m2, xbuf);
  hipLaunchKernelGGL(k_graph8, dim3(500), dim3(1024), 0, stream,
    xbuf, wTg, gb, gbnp, invdeg, begr, e_s, gbuf);
  hipLaunchKernelGGL(k_logits9, dim3(64, 8), dim3(256), 0, stream,
    xbuf, gbuf, action, nts, acw, acb, o_ws);
  hipLaunchKernelGGL(k_fc1_9, dim3(64, 4), dim3(128), 0, stream,
    o_ws, aw1, part_ws);
  hipLaunchKernelGGL(k_fc23_9, dim3(BB), dim3(512), 0, stream,
    part_ws, ab1, aw2, ab2, aw3, ab3, out);
}

// Round 13
// 288.015 us; speedup vs baseline: 1.1020x; 1.1020x over previous
//
#include <hip/hip_runtime.h>

#define SLOPE 0.01f
#define EPSV  1e-5f
#define BB    64
#define NN    500
#define TT    50
#define E_N   16000
#define FF    43
#define PP    500
#define HH    128
#define XSTRIDE 48

typedef const float* fp;

__device__ __forceinline__ float lrelu(float x){ return x >= 0.f ? x : SLOPE * x; }
__device__ __forceinline__ float bnap(float x, fp bnp, int c, int C){
  float g  = bnp[c], b_ = bnp[C + c];
  float m  = bnp[2*C + c], v = bnp[3*C + c];
  float s = g * rsqrtf(v + EPSV);
  return x * s + (b_ - m * s);
}

// ============ prep chain (unchanged) ============
__global__ __launch_bounds__(1024) void k_prep8(
    fp sc2w, fp mc2w, fp gwroot, fp gwrel,
    float* __restrict__ wT_s2, float* __restrict__ wT_m2, float* __restrict__ wTg,
    int* __restrict__ cnt, int* __restrict__ ideg)
{
  int tid = threadIdx.x, blk = blockIdx.x;
  if (blk == 0){
    for (int i = tid; i < 2880; i += 1024){ int o = i/144, x = i%144; wT_s2[x*20+o] = sc2w[i]; }
  } else if (blk == 1){
    for (int i = tid; i < 1800; i += 1024){ int o = i/90,  x = i%90;  wT_m2[x*20+o] = mc2w[i]; }
  } else if (blk < 6){
    for (int i = (blk-2)*1024 + tid; i < 9245; i += 4096){
      int f5 = i/43, g = i%43;
      wTg[i] = (f5 < 43) ? gwroot[f5*43+g] : gwrel[(f5-43)*43+g];
    }
  } else if (blk == 6){
    for (int i = tid; i < 512;  i += 1024) cnt[i] = 0;
    for (int i = tid; i < 2048; i += 1024) ideg[i] = 0;
  } else {
    for (int i = 9245 + tid; i < 9312; i += 1024) wTg[i] = 0.f;
  }
}

__global__ __launch_bounds__(256) void k_count8(
    const int* __restrict__ ei, const int* __restrict__ et,
    int* __restrict__ cnt, int* __restrict__ ideg)
{
  int i = blockIdx.x*256 + threadIdx.x;
  if (i < E_N){
    int d = ei[E_N+i], r = et[i];
    atomicAdd(&cnt[d], 1);
    atomicAdd(&ideg[r*NN+d], 1);
  }
}

__global__ __launch_bounds__(512) void k_scan8(
    const int* __restrict__ cnt, const int* __restrict__ ideg,
    int* __restrict__ begr, int* __restrict__ cursor4, float* __restrict__ inv_deg)
{
  __shared__ int sc[512];
  int tid = threadIdx.x;
  sc[tid] = cnt[tid];
  __syncthreads();
  for (int off = 1; off < 512; off <<= 1){
    int v = (tid >= off) ? sc[tid-off] : 0;
    __syncthreads();
    sc[tid] += v;
    __syncthreads();
  }
  if (tid < NN){
    int o  = tid ? sc[tid-1] : 0;
    int c1 = o  + ideg[tid];
    int c2 = c1 + ideg[NN + tid];
    int c3 = c2 + ideg[2*NN + tid];
    begr[tid*4+0] = o;  begr[tid*4+1] = c1;
    begr[tid*4+2] = c2; begr[tid*4+3] = c3;
    cursor4[tid*4+0] = o;  cursor4[tid*4+1] = c1;
    cursor4[tid*4+2] = c2; cursor4[tid*4+3] = c3;
    #pragma unroll
    for (int r = 0; r < 4; r++)
      inv_deg[r*NN+tid] = 1.f / fmaxf((float)ideg[r*NN+tid], 1.f);
  }
  if (tid == 0) begr[2000] = E_N;
}

__global__ __launch_bounds__(256) void k_fill8(
    const int* __restrict__ ei, const int* __restrict__ et,
    int* __restrict__ cursor4, int* __restrict__ e_s)
{
  int i = blockIdx.x*256 + threadIdx.x;
  if (i < E_N){
    int s = ei[i], d = ei[E_N+i], r = et[i];
    int pos = atomicAdd(&cursor4[d*4+r], 1);
    e_s[pos] = s;
  }
}

// ============ obs transpose (unchanged) ============
__global__ __launch_bounds__(256) void k_transp(
    fp obs, float* __restrict__ obsT)
{
  __shared__ float tile[64][51];
  int bx = blockIdx.x;
  int b = bx / 24, rem = bx % 24;
  int c = rem / 8, nt = rem % 8;
  int n0 = nt * 64;
  int span = (NN - n0 < 64) ? (NN - n0) : 64;
  int tid = threadIdx.x;
  const float* src = obs + ((size_t)(b*3 + c)*NN + n0)*TT;
  for (int idx = tid; idx < span*50; idx += 256)
    tile[idx/50][idx%50] = src[idx];
  __syncthreads();
  float* dst = obsT + (size_t)(b*3 + c)*50*500 + n0;
  for (int idx = tid; idx < 50*64; idx += 256){
    int t = idx >> 6, q = idx & 63;
    if (q < span) dst[(size_t)t*500 + q] = tile[q][t];
  }
}

// ============ temporal v12 (unchanged) ============
__global__ __launch_bounds__(512, 4) void k_tempo12(
    const float* __restrict__ obsT,
    fp sc1w, fp sc1b, fp sbn1, fp sc2b, fp sbn2,
    fp mc1w, fp mc1b, fp mbn1, fp mc2b, fp mbn2,
    const float* __restrict__ wT_s2, const float* __restrict__ wT_m2,
    float* __restrict__ xbuf)
{
  __shared__ float pbuf[8][64][23];
  int tid = threadIdx.x;
  int w = __builtin_amdgcn_readfirstlane(tid >> 6);
  int lane = tid & 63;
  int b  = blockIdx.x >> 3;
  int n0 = (blockIdx.x & 7) << 6;
  int span = (NN - n0 < 64) ? (NN - n0) : 64;
  int nn = n0 + lane; if (nn > NN-1) nn = NN-1;
  const float* oT = obsT + (size_t)b*3*50*500;

  if (w < 5){
    int t0 = w * 6;
    float ov[3][26];
    #pragma unroll
    for (int ci = 0; ci < 3; ci++)
      #pragma unroll
      for (int j = 0; j < 26; j++)
        ov[ci][j] = oT[(size_t)(ci*50 + t0 + j)*500 + nn];
    float sc1[3], sh1[3];
    #pragma unroll
    for (int ci = 0; ci < 3; ci++){
      float s = mbn1[ci] * rsqrtf(mbn1[9+ci] + EPSV);
      sc1[ci] = s; sh1[ci] = mbn1[3+ci] - mbn1[6+ci]*s;
    }
    float acc[20];
    #pragma unroll
    for (int o = 0; o < 20; o++) acc[o] = 0.f;
    #pragma unroll
    for (int i = 0; i < 6; i++){
      int tt = t0 + i;
      float mv[3];
      #pragma unroll
      for (int co = 0; co < 3; co++) mv[co] = mc1b[co];
      #pragma unroll
      for (int ci = 0; ci < 3; ci++)
        #pragma unroll
        for (int k = 0; k < 21; k++){
          float v = ov[ci][i + k];
          #pragma unroll
          for (int co = 0; co < 3; co++) mv[co] += v * mc1w[co*63 + ci*21 + k];
        }
      #pragma unroll
      for (int co = 0; co < 3; co++){
        float z = lrelu(mv[co]*sc1[co] + sh1[co]);
        const float* wp = wT_m2 + (co*30 + tt)*20;
        #pragma unroll
        for (int o = 0; o < 20; o++) acc[o] += z * wp[o];
      }
    }
    #pragma unroll
    for (int o = 0; o < 20; o++) pbuf[w][lane][o] = acc[o];
  } else {
    int ws_ = w - 5;
    int t0 = ws_ * 16;
    float ovs[3][18];
    #pragma unroll
    for (int ci = 0; ci < 3; ci++)
      #pragma unroll
      for (int j = 0; j < 18; j++)
        ovs[ci][j] = oT[(size_t)(ci*50 + t0 + j)*500 + nn];
    float sc1[3], sh1[3];
    #pragma unroll
    for (int ci = 0; ci < 3; ci++){
      float s = sbn1[ci] * rsqrtf(sbn1[9+ci] + EPSV);
      sc1[ci] = s; sh1[ci] = sbn1[3+ci] - sbn1[6+ci]*s;
    }
    float acc[20];
    #pragma unroll
    for (int o = 0; o < 20; o++) acc[o] = 0.f;
    #pragma unroll
    for (int i = 0; i < 16; i++){
      int tt = t0 + i;
      float sv[3];
      #pragma unroll
      for (int co = 0; co < 3; co++) sv[co] = sc1b[co];
      #pragma unroll
      for (int ci = 0; ci < 3; ci++)
        #pragma unroll
        for (int k = 0; k < 3; k++){
          float v = ovs[ci][i + k];
          #pragma unroll
          for (int co = 0; co < 3; co++) sv[co] += v * sc1w[co*9 + ci*3 + k];
        }
      #pragma unroll
      for (int co = 0; co < 3; co++){
        float z = lrelu(sv[co]*sc1[co] + sh1[co]);
        const float* wp = wT_s2 + (co*48 + tt)*20;
        #pragma unroll
        for (int o = 0; o < 20; o++) acc[o] += z * wp[o];
      }
    }
    #pragma unroll
    for (int o = 0; o < 20; o++) pbuf[w][lane][o] = acc[o];
    int l0 = ws_ * 17;
    int ln = (50 - l0 < 17) ? (50 - l0) : 17;
    float mx[3] = {-1e30f, -1e30f, -1e30f};
    for (int j = 0; j < ln; j++){
      #pragma unroll
      for (int c = 0; c < 3; c++)
        mx[c] = fmaxf(mx[c], oT[(size_t)(c*50 + l0 + j)*500 + nn]);
    }
    #pragma unroll
    for (int c = 0; c < 3; c++) pbuf[w][lane][20 + c] = mx[c];
  }
  __syncthreads();

  size_t gx = (size_t)(b*NN + n0)*XSTRIDE;
  for (int idx = tid; idx < 64*20; idx += 512){
    int n = idx / 20, o = idx % 20;
    if (n < span){
      float v = pbuf[0][n][o] + pbuf[1][n][o] + pbuf[2][n][o]
              + pbuf[3][n][o] + pbuf[4][n][o];
      xbuf[gx + (size_t)n*XSTRIDE + 20 + o] = lrelu(bnap(v + mc2b[o], mbn2, o, 20));
    }
  }
  for (int idx = tid; idx < 64*20; idx += 512){
    int n = idx / 20, o = idx % 20;
    if (n < span){
      float v = pbuf[5][n][o] + pbuf[6][n][o] + pbuf[7][n][o];
      xbuf[gx + (size_t)n*XSTRIDE + o] = lrelu(bnap(v + sc2b[o], sbn2, o, 20));
    }
  }
  for (int idx = tid; idx < 64*3; idx += 512){
    int n = idx / 3, c = idx % 3;
    if (n < span){
      float v = fmaxf(fmaxf(pbuf[5][n][20+c], pbuf[6][n][20+c]), pbuf[7][n][20+c]);
      xbuf[gx + (size_t)n*XSTRIDE + 40 + c] = lrelu(v);
    }
  }
}

// ============ graph v13: XCD-aware block permute + 4-deep gather pipeline ====
__global__ __launch_bounds__(1024) void k_graph13(
    const float* __restrict__ xbuf, const float* __restrict__ wTg,
    fp gb, fp gbnp, const float* __restrict__ inv_deg,
    const int* __restrict__ begr, const int* __restrict__ e_s,
    float* __restrict__ gbuf)
{
  __shared__ float xin[64][219];
  int p = blockIdx.x;                         // 0..503
  int l = ((p & 7) * 63) + (p >> 3);          // same-b blocks -> same XCD (if %8 rr)
  if (l >= 500) return;
  int tid = threadIdx.x;
  int w = tid >> 6, lane = tid & 63;
  int g0 = l * 64;

  for (int q = 0; q < 4; q++){
    int nl = (w << 2) + q;
    int g = __builtin_amdgcn_readfirstlane(g0 + nl);
    int b = g / NN;
    int n = g - b * NN;
    const float* xb = xbuf + (size_t)(b * NN) * XSTRIDE;
    float xv = (lane < FF) ? xbuf[(size_t)g*XSTRIDE + lane] : 0.f;
    float ar[4];
    #pragma unroll
    for (int r = 0; r < 4; r++){
      int beg = __builtin_amdgcn_readfirstlane(begr[n*4 + r]);
      int end = __builtin_amdgcn_readfirstlane(begr[n*4 + r + 1]);
      float a0 = 0.f, a1 = 0.f, a2 = 0.f, a3 = 0.f;
      int i = beg;
      for (; i + 4 <= end; i += 4){
        int s0 = e_s[i], s1 = e_s[i+1], s2 = e_s[i+2], s3 = e_s[i+3];
        float v0 = (lane < FF) ? xb[(size_t)s0*XSTRIDE + lane] : 0.f;
        float v1 = (lane < FF) ? xb[(size_t)s1*XSTRIDE + lane] : 0.f;
        float v2 = (lane < FF) ? xb[(size_t)s2*XSTRIDE + lane] : 0.f;
        float v3 = (lane < FF) ? xb[(size_t)s3*XSTRIDE + lane] : 0.f;
        a0 += v0; a1 += v1; a2 += v2; a3 += v3;
      }
      for (; i < end; i++){
        int s = e_s[i];
        a0 += (lane < FF) ? xb[(size_t)s*XSTRIDE + lane] : 0.f;
      }
      ar[r] = ((a0 + a1) + (a2 + a3)) * inv_deg[r*NN + n];
    }
    if (lane < FF){
      xin[nl][lane]       = xv;
      xin[nl][ 43 + lane] = ar[0];
      xin[nl][ 86 + lane] = ar[1];
      xin[nl][129 + lane] = ar[2];
      xin[nl][172 + lane] = ar[3];
    }
  }
  __syncthreads();

  int c0 = __builtin_amdgcn_readfirstlane(w * 3);
  int g = g0 + lane;
  float acc[3];
  #pragma unroll
  for (int j = 0; j < 3; j++) acc[j] = (c0 + j < FF) ? gb[c0+j] : 0.f;
  for (int f = 0; f < 215; f++){
    float v = xin[lane][f];
    const float* wp = wTg + f*43 + c0;
    #pragma unroll
    for (int j = 0; j < 3; j++) acc[j] += v * wp[j];
  }
  #pragma unroll
  for (int j = 0; j < 3; j++){
    int c = c0 + j;
    if (c < FF)
      gbuf[(size_t)g*XSTRIDE + c] = lrelu(bnap(acc[j], gbnp, c, FF));
  }
}

// ============ head (logits unchanged; fc1 8 chunks; fc23 8-partials) ========
__global__ __launch_bounds__(256) void k_logits9(
    const float* __restrict__ xbuf, const float* __restrict__ gbuf,
    fp action, const int* __restrict__ nts, fp acw, fp acb,
    float* __restrict__ o_ws)
{
  __shared__ float feats[64][87];
  int b = blockIdx.x, tile = blockIdx.y;
  int tid = threadIdx.x;
  int p0 = tile * 64;
  int span = (PP - p0 < 64) ? (PP - p0) : 64;

  for (int j = tid; j < span*86; j += 256){
    int q = j / 86, c = j % 86;
    int np = nts[p0 + q];
    size_t row = (size_t)(b*NN + np)*XSTRIDE;
    feats[q][c] = (c < FF) ? xbuf[row + c] : gbuf[row + (c - FF)];
  }
  __syncthreads();
  if (tid < span){
    int p = p0 + tid;
    float acc = acb[0] + action[b*(PP+1) + 1 + p] * acw[0];
    #pragma unroll 2
    for (int c = 0; c < 86; c++) acc += feats[tid][c] * acw[1 + c];
    o_ws[b*(PP+1) + 1 + p] = acc;
  }
  if (tile == 0 && tid == 64) o_ws[b*(PP+1)] = 0.f;
}

__global__ __launch_bounds__(128) void k_fc1_13(
    const float* __restrict__ o_ws, fp aw1, float* __restrict__ part_ws)
{
  __shared__ float os[63];
  int b = blockIdx.x, chunk = blockIdx.y;      // 8 chunks of 63 (last 60)
  int tid = threadIdx.x;
  int k0 = chunk * 63;
  int kn = (chunk == 7) ? (501 - 441) : 63;
  if (tid < kn) os[tid] = o_ws[b*(PP+1) + k0 + tid];
  __syncthreads();
  float acc = 0.f;
  for (int k = 0; k < kn; k++) acc += os[k] * aw1[(k0+k)*HH + tid];
  part_ws[(b*8 + chunk)*HH + tid] = acc;
}

__global__ __launch_bounds__(512) void k_fc23_13(
    const float* __restrict__ part_ws,
    fp ab1, fp aw2, fp ab2, fp aw3, fp ab3,
    float* __restrict__ out)
{
  int b = blockIdx.x;
  int tid = threadIdx.x;
  __shared__ float h1[HH];
  __shared__ float h2[HH];
  __shared__ float red[512];

  if (tid < HH){
    const float* pw = part_ws + b*8*HH;
    float v = ab1[tid];
    #pragma unroll
    for (int j = 0; j < 8; j++) v += pw[j*HH + tid];
    h1[tid] = fmaxf(v, 0.f);
  }
  __syncthreads();
  if (tid < HH){
    float acc = ab2[tid];
    #pragma unroll 4
    for (int k = 0; k < HH; k++) acc += h1[k] * aw2[k*HH + tid];
    h2[tid] = fmaxf(acc, 0.f);
  }
  __syncthreads();

  float val = -1e30f;
  if (tid <= PP){
    float acc = ab3[tid];
    #pragma unroll 4
    for (int k = 0; k < HH; k++) acc += h2[k] * aw3[k*(PP+1) + tid];
    val = acc;
  }
  red[tid] = val;
  __syncthreads();
  for (int s = 256; s > 0; s >>= 1){
    if (tid < s) red[tid] = fmaxf(red[tid], red[tid + s]);
    __syncthreads();
  }
  float mx = red[0];
  __syncthreads();
  float e = (tid <= PP) ? expf(val - mx) : 0.f;
  red[tid] = e;
  __syncthreads();
  for (int s = 256; s > 0; s >>= 1){
    if (tid < s) red[tid] += red[tid + s];
    __syncthreads();
  }
  float sum = red[0];
  if (tid <= PP) out[b*(PP+1) + tid] = e / sum;
}

extern "C" void kernel_launch(void* const* d_in, const int* in_sizes, int n_in,
                              void* d_out, int out_size, void* d_ws, size_t ws_size,
                              hipStream_t stream)
{
  fp obs    = (fp)d_in[0];
  fp action = (fp)d_in[1];
  const int* ei  = (const int*)d_in[2];
  const int* et  = (const int*)d_in[3];
  const int* nts = (const int*)d_in[4];
  fp sc1w=(fp)d_in[5],  sc1b=(fp)d_in[6],  sbn1=(fp)d_in[7];
  fp sc2w=(fp)d_in[8],  sc2b=(fp)d_in[9],  sbn2=(fp)d_in[10];
  fp mc1w=(fp)d_in[11], mc1b=(fp)d_in[12], mbn1=(fp)d_in[13];
  fp mc2w=(fp)d_in[14], mc2b=(fp)d_in[15], mbn2=(fp)d_in[16];
  fp gwroot=(fp)d_in[17], gwrel=(fp)d_in[18], gb=(fp)d_in[19], gbnp=(fp)d_in[20];
  fp acw=(fp)d_in[21], acb=(fp)d_in[22];
  fp aw1=(fp)d_in[23], ab1=(fp)d_in[24];
  fp aw2=(fp)d_in[25], ab2=(fp)d_in[26];
  fp aw3=(fp)d_in[27], ab3=(fp)d_in[28];

  float* xbuf   = (float*)d_ws;              // 1,536,000
  float* obsT   = xbuf + 1536000;            // 4,800,000 (dead after tempo)
  float* gbuf   = obsT;                      // aliases obsT
  float* wT_s2  = obsT + 4800000;            // 2880
  float* wT_m2  = wT_s2 + 2880;              // 1800
  float* wTg    = wT_m2 + 1800;              // 9312
  float* invdeg = wTg + 9312;                // 2000
  int*   ip     = (int*)(invdeg + 2000);
  int* cnt     = ip;            // 512
  int* ideg    = ip + 512;      // 2048
  int* begr    = ip + 2560;     // 2001
  int* cursor4 = ip + 4561;     // 2000
  int* e_s     = ip + 6561;     // 16000
  float* o_ws    = (float*)(ip + 22561);     // 64*501
  float* part_ws = o_ws + 32064;             // 64*8*128

  float* out = (float*)d_out;

  hipLaunchKernelGGL(k_prep8, dim3(8), dim3(1024), 0, stream,
    sc2w, mc2w, gwroot, gwrel, wT_s2, wT_m2, wTg, cnt, ideg);
  hipLaunchKernelGGL(k_count8, dim3(63), dim3(256), 0, stream,
    ei, et, cnt, ideg);
  hipLaunchKernelGGL(k_scan8, dim3(1), dim3(512), 0, stream,
    cnt, ideg, begr, cursor4, invdeg);
  hipLaunchKernelGGL(k_fill8, dim3(63), dim3(256), 0, stream,
    ei, et, cursor4, e_s);
  hipLaunchKernelGGL(k_transp, dim3(64*3*8), dim3(256), 0, stream,
    obs, obsT);
  hipLaunchKernelGGL(k_tempo12, dim3(512), dim3(512), 0, stream,
    obsT, sc1w, sc1b, sbn1, sc2b, sbn2,
    mc1w, mc1b, mbn1, mc2b, mbn2, wT_s2, wT_m2, xbuf);
  hipLaunchKernelGGL(k_graph13, dim3(504), dim3(1024), 0, stream,
    xbuf, wTg, gb, gbnp, invdeg, begr, e_s, gbuf);
  hipLaunchKernelGGL(k_logits9, dim3(64, 8), dim3(256), 0, stream,
    xbuf, gbuf, action, nts, acw, acb, o_ws);
  hipLaunchKernelGGL(k_fc1_13, dim3(64, 8), dim3(128), 0, stream,
    o_ws, aw1, part_ws);
  hipLaunchKernelGGL(k_fc23_13, dim3(BB), dim3(512), 0, stream,
    part_ws, ab1, aw2, ab2, aw3, ab3, out);
}

// Round 14
// 271.073 us; speedup vs baseline: 1.1709x; 1.0625x over previous
//
#include <hip/hip_runtime.h>

#define SLOPE 0.01f
#define EPSV  1e-5f
#define BB    64
#define NN    500
#define TT    50
#define E_N   16000
#define FF    43
#define PP    500
#define HH    128
#define XSTRIDE 48

typedef const float* fp;

__device__ __forceinline__ float lrelu(float x){ return x >= 0.f ? x : SLOPE * x; }
__device__ __forceinline__ float bnap(float x, fp bnp, int c, int C){
  float g  = bnp[c], b_ = bnp[C + c];
  float m  = bnp[2*C + c], v = bnp[3*C + c];
  float s = g * rsqrtf(v + EPSV);
  return x * s + (b_ - m * s);
}

// ============ prep chain (unchanged) ============
__global__ __launch_bounds__(1024) void k_prep8(
    fp sc2w, fp mc2w, fp gwroot, fp gwrel,
    float* __restrict__ wT_s2, float* __restrict__ wT_m2, float* __restrict__ wTg,
    int* __restrict__ cnt, int* __restrict__ ideg)
{
  int tid = threadIdx.x, blk = blockIdx.x;
  if (blk == 0){
    for (int i = tid; i < 2880; i += 1024){ int o = i/144, x = i%144; wT_s2[x*20+o] = sc2w[i]; }
  } else if (blk == 1){
    for (int i = tid; i < 1800; i += 1024){ int o = i/90,  x = i%90;  wT_m2[x*20+o] = mc2w[i]; }
  } else if (blk < 6){
    for (int i = (blk-2)*1024 + tid; i < 9245; i += 4096){
      int f5 = i/43, g = i%43;
      wTg[i] = (f5 < 43) ? gwroot[f5*43+g] : gwrel[(f5-43)*43+g];
    }
  } else if (blk == 6){
    for (int i = tid; i < 512;  i += 1024) cnt[i] = 0;
    for (int i = tid; i < 2048; i += 1024) ideg[i] = 0;
  } else {
    for (int i = 9245 + tid; i < 9312; i += 1024) wTg[i] = 0.f;
  }
}

__global__ __launch_bounds__(256) void k_count8(
    const int* __restrict__ ei, const int* __restrict__ et,
    int* __restrict__ cnt, int* __restrict__ ideg)
{
  int i = blockIdx.x*256 + threadIdx.x;
  if (i < E_N){
    int d = ei[E_N+i], r = et[i];
    atomicAdd(&cnt[d], 1);
    atomicAdd(&ideg[r*NN+d], 1);
  }
}

__global__ __launch_bounds__(512) void k_scan8(
    const int* __restrict__ cnt, const int* __restrict__ ideg,
    int* __restrict__ begr, int* __restrict__ cursor4, float* __restrict__ inv_deg)
{
  __shared__ int sc[512];
  int tid = threadIdx.x;
  sc[tid] = cnt[tid];
  __syncthreads();
  for (int off = 1; off < 512; off <<= 1){
    int v = (tid >= off) ? sc[tid-off] : 0;
    __syncthreads();
    sc[tid] += v;
    __syncthreads();
  }
  if (tid < NN){
    int o  = tid ? sc[tid-1] : 0;
    int c1 = o  + ideg[tid];
    int c2 = c1 + ideg[NN + tid];
    int c3 = c2 + ideg[2*NN + tid];
    begr[tid*4+0] = o;  begr[tid*4+1] = c1;
    begr[tid*4+2] = c2; begr[tid*4+3] = c3;
    cursor4[tid*4+0] = o;  cursor4[tid*4+1] = c1;
    cursor4[tid*4+2] = c2; cursor4[tid*4+3] = c3;
    #pragma unroll
    for (int r = 0; r < 4; r++)
      inv_deg[r*NN+tid] = 1.f / fmaxf((float)ideg[r*NN+tid], 1.f);
  }
  if (tid == 0) begr[2000] = E_N;
}

__global__ __launch_bounds__(256) void k_fill8(
    const int* __restrict__ ei, const int* __restrict__ et,
    int* __restrict__ cursor4, int* __restrict__ e_s)
{
  int i = blockIdx.x*256 + threadIdx.x;
  if (i < E_N){
    int s = ei[i], d = ei[E_N+i], r = et[i];
    int pos = atomicAdd(&cursor4[d*4+r], 1);
    e_s[pos] = s;
  }
}

// ============ temporal v14: fused LDS transpose + register-window compute ====
// 512 blocks (b, n-tile) x 512 thr. Stage obs (native, coalesced) -> ol LDS;
// load per-wave windows from LDS (stride 151 = conflict-free); compute with
// only s_load weights; pbuf ALIASES ol (47 KB total).
__global__ __launch_bounds__(512, 2) void k_tempo14(
    fp obs,
    fp sc1w, fp sc1b, fp sbn1, fp sc2b, fp sbn2,
    fp mc1w, fp mc1b, fp mbn1, fp mc2b, fp mbn2,
    const float* __restrict__ wT_s2, const float* __restrict__ wT_m2,
    float* __restrict__ xbuf)
{
  __shared__ float smem[11776];                 // max(64*151=9664, 8*64*23=11776)
  #define OL(n,j)   smem[(n)*151 + (j)]
  #define PB(w,n,o) smem[(w)*1472 + (n)*23 + (o)]
  int tid = threadIdx.x;
  int w = __builtin_amdgcn_readfirstlane(tid >> 6);
  int lane = tid & 63;
  int b  = blockIdx.x >> 3;
  int n0 = (blockIdx.x & 7) << 6;
  int span = (NN - n0 < 64) ? (NN - n0) : 64;

  // stage: obs[b][c][n0+n][t] -> OL(n, c*50+t); rows >= span clamp to node 499
  for (int c = 0; c < 3; c++){
    const float* base = obs + (size_t)(b*3 + c)*25000;
    for (int idx = tid; idx < 3200; idx += 512){
      int n = idx / 50, t = idx % 50;
      int node = n0 + n; if (node > NN-1) node = NN-1;
      OL(n, c*50 + t) = base[node*50 + t];
    }
  }
  __syncthreads();

  float acc[20];
  float mx[3] = {-1e30f, -1e30f, -1e30f};
  if (w < 5){
    // m-branch: t' in [w*6, w*6+6); window 26 wide
    int t0 = w * 6;
    float ov[3][26];
    #pragma unroll
    for (int ci = 0; ci < 3; ci++)
      #pragma unroll
      for (int j = 0; j < 26; j++)
        ov[ci][j] = OL(lane, ci*50 + t0 + j);
    float sc1[3], sh1[3];
    #pragma unroll
    for (int ci = 0; ci < 3; ci++){
      float s = mbn1[ci] * rsqrtf(mbn1[9+ci] + EPSV);
      sc1[ci] = s; sh1[ci] = mbn1[3+ci] - mbn1[6+ci]*s;
    }
    #pragma unroll
    for (int o = 0; o < 20; o++) acc[o] = 0.f;
    #pragma unroll
    for (int i = 0; i < 6; i++){
      int tt = t0 + i;
      float mv[3];
      #pragma unroll
      for (int co = 0; co < 3; co++) mv[co] = mc1b[co];
      #pragma unroll
      for (int ci = 0; ci < 3; ci++)
        #pragma unroll
        for (int k = 0; k < 21; k++){
          float v = ov[ci][i + k];
          #pragma unroll
          for (int co = 0; co < 3; co++) mv[co] += v * mc1w[co*63 + ci*21 + k];
        }
      #pragma unroll
      for (int co = 0; co < 3; co++){
        float z = lrelu(mv[co]*sc1[co] + sh1[co]);
        const float* wp = wT_m2 + (co*30 + tt)*20;
        #pragma unroll
        for (int o = 0; o < 20; o++) acc[o] += z * wp[o];
      }
    }
  } else {
    // s-branch: t' in [(w-5)*16, +16); window 18 wide; plus l-max slice
    int ws_ = w - 5;
    int t0 = ws_ * 16;
    float ovs[3][18];
    #pragma unroll
    for (int ci = 0; ci < 3; ci++)
      #pragma unroll
      for (int j = 0; j < 18; j++)
        ovs[ci][j] = OL(lane, ci*50 + t0 + j);
    int l0 = ws_ * 17;
    int ln = (50 - l0 < 17) ? (50 - l0) : 17;
    for (int j = 0; j < ln; j++){
      #pragma unroll
      for (int c = 0; c < 3; c++)
        mx[c] = fmaxf(mx[c], OL(lane, c*50 + l0 + j));
    }
    float sc1[3], sh1[3];
    #pragma unroll
    for (int ci = 0; ci < 3; ci++){
      float s = sbn1[ci] * rsqrtf(sbn1[9+ci] + EPSV);
      sc1[ci] = s; sh1[ci] = sbn1[3+ci] - sbn1[6+ci]*s;
    }
    #pragma unroll
    for (int o = 0; o < 20; o++) acc[o] = 0.f;
    #pragma unroll
    for (int i = 0; i < 16; i++){
      int tt = t0 + i;
      float sv[3];
      #pragma unroll
      for (int co = 0; co < 3; co++) sv[co] = sc1b[co];
      #pragma unroll
      for (int ci = 0; ci < 3; ci++)
        #pragma unroll
        for (int k = 0; k < 3; k++){
          float v = ovs[ci][i + k];
          #pragma unroll
          for (int co = 0; co < 3; co++) sv[co] += v * sc1w[co*9 + ci*3 + k];
        }
      #pragma unroll
      for (int co = 0; co < 3; co++){
        float z = lrelu(sv[co]*sc1[co] + sh1[co]);
        const float* wp = wT_s2 + (co*48 + tt)*20;
        #pragma unroll
        for (int o = 0; o < 20; o++) acc[o] += z * wp[o];
      }
    }
  }
  __syncthreads();   // all OL reads done -> safe to overwrite with PB

  #pragma unroll
  for (int o = 0; o < 20; o++) PB(w, lane, o) = acc[o];
  if (w >= 5){
    #pragma unroll
    for (int c = 0; c < 3; c++) PB(w, lane, 20 + c) = mx[c];
  }
  __syncthreads();

  size_t gx = (size_t)(b*NN + n0)*XSTRIDE;
  for (int idx = tid; idx < 64*20; idx += 512){
    int n = idx / 20, o = idx % 20;
    if (n < span){
      float v = PB(0,n,o) + PB(1,n,o) + PB(2,n,o) + PB(3,n,o) + PB(4,n,o);
      xbuf[gx + (size_t)n*XSTRIDE + 20 + o] = lrelu(bnap(v + mc2b[o], mbn2, o, 20));
    }
  }
  for (int idx = tid; idx < 64*20; idx += 512){
    int n = idx / 20, o = idx % 20;
    if (n < span){
      float v = PB(5,n,o) + PB(6,n,o) + PB(7,n,o);
      xbuf[gx + (size_t)n*XSTRIDE + o] = lrelu(bnap(v + sc2b[o], sbn2, o, 20));
    }
  }
  for (int idx = tid; idx < 64*3; idx += 512){
    int n = idx / 3, c = idx % 3;
    if (n < span){
      float v = fmaxf(fmaxf(PB(5,n,20+c), PB(6,n,20+c)), PB(7,n,20+c));
      xbuf[gx + (size_t)n*XSTRIDE + 40 + c] = lrelu(v);
    }
  }
  #undef OL
  #undef PB
}

// ============ graph v13 (unchanged) ============
__global__ __launch_bounds__(1024) void k_graph13(
    const float* __restrict__ xbuf, const float* __restrict__ wTg,
    fp gb, fp gbnp, const float* __restrict__ inv_deg,
    const int* __restrict__ begr, const int* __restrict__ e_s,
    float* __restrict__ gbuf)
{
  __shared__ float xin[64][219];
  int p = blockIdx.x;
  int l = ((p & 7) * 63) + (p >> 3);
  if (l >= 500) return;
  int tid = threadIdx.x;
  int w = tid >> 6, lane = tid & 63;
  int g0 = l * 64;

  for (int q = 0; q < 4; q++){
    int nl = (w << 2) + q;
    int g = __builtin_amdgcn_readfirstlane(g0 + nl);
    int b = g / NN;
    int n = g - b * NN;
    const float* xb = xbuf + (size_t)(b * NN) * XSTRIDE;
    float xv = (lane < FF) ? xbuf[(size_t)g*XSTRIDE + lane] : 0.f;
    float ar[4];
    #pragma unroll
    for (int r = 0; r < 4; r++){
      int beg = __builtin_amdgcn_readfirstlane(begr[n*4 + r]);
      int end = __builtin_amdgcn_readfirstlane(begr[n*4 + r + 1]);
      float a0 = 0.f, a1 = 0.f, a2 = 0.f, a3 = 0.f;
      int i = beg;
      for (; i + 4 <= end; i += 4){
        int s0 = e_s[i], s1 = e_s[i+1], s2 = e_s[i+2], s3 = e_s[i+3];
        float v0 = (lane < FF) ? xb[(size_t)s0*XSTRIDE + lane] : 0.f;
        float v1 = (lane < FF) ? xb[(size_t)s1*XSTRIDE + lane] : 0.f;
        float v2 = (lane < FF) ? xb[(size_t)s2*XSTRIDE + lane] : 0.f;
        float v3 = (lane < FF) ? xb[(size_t)s3*XSTRIDE + lane] : 0.f;
        a0 += v0; a1 += v1; a2 += v2; a3 += v3;
      }
      for (; i < end; i++){
        int s = e_s[i];
        a0 += (lane < FF) ? xb[(size_t)s*XSTRIDE + lane] : 0.f;
      }
      ar[r] = ((a0 + a1) + (a2 + a3)) * inv_deg[r*NN + n];
    }
    if (lane < FF){
      xin[nl][lane]       = xv;
      xin[nl][ 43 + lane] = ar[0];
      xin[nl][ 86 + lane] = ar[1];
      xin[nl][129 + lane] = ar[2];
      xin[nl][172 + lane] = ar[3];
    }
  }
  __syncthreads();

  int c0 = __builtin_amdgcn_readfirstlane(w * 3);
  int g = g0 + lane;
  float acc[3];
  #pragma unroll
  for (int j = 0; j < 3; j++) acc[j] = (c0 + j < FF) ? gb[c0+j] : 0.f;
  for (int f = 0; f < 215; f++){
    float v = xin[lane][f];
    const float* wp = wTg + f*43 + c0;
    #pragma unroll
    for (int j = 0; j < 3; j++) acc[j] += v * wp[j];
  }
  #pragma unroll
  for (int j = 0; j < 3; j++){
    int c = c0 + j;
    if (c < FF)
      gbuf[(size_t)g*XSTRIDE + c] = lrelu(bnap(acc[j], gbnp, c, FF));
  }
}

// ============ logits (unchanged) ============
__global__ __launch_bounds__(256) void k_logits9(
    const float* __restrict__ xbuf, const float* __restrict__ gbuf,
    fp action, const int* __restrict__ nts, fp acw, fp acb,
    float* __restrict__ o_ws)
{
  __shared__ float feats[64][87];
  int b = blockIdx.x, tile = blockIdx.y;
  int tid = threadIdx.x;
  int p0 = tile * 64;
  int span = (PP - p0 < 64) ? (PP - p0) : 64;

  for (int j = tid; j < span*86; j += 256){
    int q = j / 86, c = j % 86;
    int np = nts[p0 + q];
    size_t row = (size_t)(b*NN + np)*XSTRIDE;
    feats[q][c] = (c < FF) ? xbuf[row + c] : gbuf[row + (c - FF)];
  }
  __syncthreads();
  if (tid < span){
    int p = p0 + tid;
    float acc = acb[0] + action[b*(PP+1) + 1 + p] * acw[0];
    #pragma unroll 2
    for (int c = 0; c < 86; c++) acc += feats[tid][c] * acw[1 + c];
    o_ws[b*(PP+1) + 1 + p] = acc;
  }
  if (tile == 0 && tid == 64) o_ws[b*(PP+1)] = 0.f;
}

// ============ fc1+fc2+fc3+softmax fused; 64 blocks x 512 ============
__global__ __launch_bounds__(512) void k_fcall(
    const float* __restrict__ o_ws,
    fp aw1, fp ab1, fp aw2, fp ab2, fp aw3, fp ab3,
    float* __restrict__ out)
{
  int b = blockIdx.x;
  int tid = threadIdx.x;
  __shared__ float os[PP+1];
  __shared__ float part[4][HH];
  __shared__ float h1[HH];
  __shared__ float h2[HH];
  __shared__ float red[512];

  if (tid <= PP) os[tid] = o_ws[b*(PP+1) + tid];
  __syncthreads();

  {
    int chunk = tid >> 7, h = tid & 127;
    int k0 = chunk * 125;
    int kn = (chunk == 3) ? 126 : 125;
    float acc = 0.f;
    for (int k = 0; k < kn; k++) acc += os[k0+k] * aw1[(k0+k)*HH + h];
    part[chunk][h] = acc;
  }
  __syncthreads();
  if (tid < HH)
    h1[tid] = fmaxf(ab1[tid] + part[0][tid] + part[1][tid] + part[2][tid] + part[3][tid], 0.f);
  __syncthreads();
  if (tid < HH){
    float acc = ab2[tid];
    #pragma unroll 4
    for (int k = 0; k < HH; k++) acc += h1[k] * aw2[k*HH + tid];
    h2[tid] = fmaxf(acc, 0.f);
  }
  __syncthreads();

  float val = -1e30f;
  if (tid <= PP){
    float acc = ab3[tid];
    #pragma unroll 4
    for (int k = 0; k < HH; k++) acc += h2[k] * aw3[k*(PP+1) + tid];
    val = acc;
  }
  red[tid] = val;
  __syncthreads();
  for (int s = 256; s > 0; s >>= 1){
    if (tid < s) red[tid] = fmaxf(red[tid], red[tid + s]);
    __syncthreads();
  }
  float mxv = red[0];
  __syncthreads();
  float e = (tid <= PP) ? expf(val - mxv) : 0.f;
  red[tid] = e;
  __syncthreads();
  for (int s = 256; s > 0; s >>= 1){
    if (tid < s) red[tid] += red[tid + s];
    __syncthreads();
  }
  float sum = red[0];
  if (tid <= PP) out[b*(PP+1) + tid] = e / sum;
}

extern "C" void kernel_launch(void* const* d_in, const int* in_sizes, int n_in,
                              void* d_out, int out_size, void* d_ws, size_t ws_size,
                              hipStream_t stream)
{
  fp obs    = (fp)d_in[0];
  fp action = (fp)d_in[1];
  const int* ei  = (const int*)d_in[2];
  const int* et  = (const int*)d_in[3];
  const int* nts = (const int*)d_in[4];
  fp sc1w=(fp)d_in[5],  sc1b=(fp)d_in[6],  sbn1=(fp)d_in[7];
  fp sc2w=(fp)d_in[8],  sc2b=(fp)d_in[9],  sbn2=(fp)d_in[10];
  fp mc1w=(fp)d_in[11], mc1b=(fp)d_in[12], mbn1=(fp)d_in[13];
  fp mc2w=(fp)d_in[14], mc2b=(fp)d_in[15], mbn2=(fp)d_in[16];
  fp gwroot=(fp)d_in[17], gwrel=(fp)d_in[18], gb=(fp)d_in[19], gbnp=(fp)d_in[20];
  fp acw=(fp)d_in[21], acb=(fp)d_in[22];
  fp aw1=(fp)d_in[23], ab1=(fp)d_in[24];
  fp aw2=(fp)d_in[25], ab2=(fp)d_in[26];
  fp aw3=(fp)d_in[27], ab3=(fp)d_in[28];

  float* xbuf   = (float*)d_ws;              // 1,536,000
  float* gbuf   = xbuf + 1536000;            // 1,536,000
  float* wT_s2  = gbuf + 1536000;            // 2880
  float* wT_m2  = wT_s2 + 2880;              // 1800
  float* wTg    = wT_m2 + 1800;              // 9312
  float* invdeg = wTg + 9312;                // 2000
  int*   ip     = (int*)(invdeg + 2000);
  int* cnt     = ip;            // 512
  int* ideg    = ip + 512;      // 2048
  int* begr    = ip + 2560;     // 2001
  int* cursor4 = ip + 4561;     // 2000
  int* e_s     = ip + 6561;     // 16000
  float* o_ws  = (float*)(ip + 22561);       // 64*501

  float* out = (float*)d_out;

  hipLaunchKernelGGL(k_prep8, dim3(8), dim3(1024), 0, stream,
    sc2w, mc2w, gwroot, gwrel, wT_s2, wT_m2, wTg, cnt, ideg);
  hipLaunchKernelGGL(k_count8, dim3(63), dim3(256), 0, stream,
    ei, et, cnt, ideg);
  hipLaunchKernelGGL(k_scan8, dim3(1), dim3(512), 0, stream,
    cnt, ideg, begr, cursor4, invdeg);
  hipLaunchKernelGGL(k_fill8, dim3(63), dim3(256), 0, stream,
    ei, et, cursor4, e_s);
  hipLaunchKernelGGL(k_tempo14, dim3(512), dim3(512), 0, stream,
    obs, sc1w, sc1b, sbn1, sc2b, sbn2,
    mc1w, mc1b, mbn1, mc2b, mbn2, wT_s2, wT_m2, xbuf);
  hipLaunchKernelGGL(k_graph13, dim3(504), dim3(1024), 0, stream,
    xbuf, wTg, gb, gbnp, invdeg, begr, e_s, gbuf);
  hipLaunchKernelGGL(k_logits9, dim3(64, 8), dim3(256), 0, stream,
    xbuf, gbuf, action, nts, acw, acb, o_ws);
  hipLaunchKernelGGL(k_fcall, dim3(BB), dim3(512), 0, stream,
    o_ws, aw1, ab1, aw2, ab2, aw3, ab3, out);
}

// Round 15
// 265.820 us; speedup vs baseline: 1.1940x; 1.0198x over previous
//
#include <hip/hip_runtime.h>

#define SLOPE 0.01f
#define EPSV  1e-5f
#define BB    64
#define NN    500
#define TT    50
#define E_N   16000
#define FF    43
#define PP    500
#define HH    128
#define XSTRIDE 48

typedef const float* fp;

__device__ __forceinline__ float lrelu(float x){ return x >= 0.f ? x : SLOPE * x; }
__device__ __forceinline__ float bnap(float x, fp bnp, int c, int C){
  float g  = bnp[c], b_ = bnp[C + c];
  float m  = bnp[2*C + c], v = bnp[3*C + c];
  float s = g * rsqrtf(v + EPSV);
  return x * s + (b_ - m * s);
}

// ============ prep: weight transposes + o_ws col-0 zero (8 blocks) ============
__global__ __launch_bounds__(1024) void k_prep15(
    fp sc2w, fp mc2w, fp gwroot, fp gwrel,
    float* __restrict__ wT_s2, float* __restrict__ wT_m2, float* __restrict__ wTg,
    float* __restrict__ o_ws)
{
  int tid = threadIdx.x, blk = blockIdx.x;
  if (blk == 0){
    for (int i = tid; i < 2880; i += 1024){ int o = i/144, x = i%144; wT_s2[x*20+o] = sc2w[i]; }
  } else if (blk == 1){
    for (int i = tid; i < 1800; i += 1024){ int o = i/90,  x = i%90;  wT_m2[x*20+o] = mc2w[i]; }
  } else if (blk < 6){
    for (int i = (blk-2)*1024 + tid; i < 9245; i += 4096){
      int f5 = i/43, g = i%43;
      wTg[i] = (f5 < 43) ? gwroot[f5*43+g] : gwrel[(f5-43)*43+g];
    }
  } else if (blk == 6){
    if (tid < BB) o_ws[tid*(PP+1)] = 0.f;
  } else {
    for (int i = 9245 + tid; i < 9312; i += 1024) wTg[i] = 0.f;
  }
}

// ============ tempo15: 512 tempo blocks + block 512 = CSR build =============
// tempo core identical to r14 (fused LDS transpose + register windows + s_load
// weights + aliased pbuf). CSR block (LDS histogram/scan/fill) hides under it.
__global__ __launch_bounds__(512, 2) void k_tempo15(
    fp obs,
    fp sc1w, fp sc1b, fp sbn1, fp sc2b, fp sbn2,
    fp mc1w, fp mc1b, fp mbn1, fp mc2b, fp mbn2,
    const float* __restrict__ wT_s2, const float* __restrict__ wT_m2,
    float* __restrict__ xbuf,
    const int* __restrict__ ei, const int* __restrict__ et,
    int* __restrict__ begr, int* __restrict__ e_s, float* __restrict__ inv_deg)
{
  __shared__ float smem[11776];                 // 47104 B (union of OL / PB / CSR)
  #define OL(n,j)   smem[(n)*151 + (j)]
  #define PB(w,n,o) smem[(w)*1472 + (n)*23 + (o)]
  int tid = threadIdx.x;

  if (blockIdx.x == 512){
    // ---------------- CSR build (one block, 512 threads) ----------------
    int* S   = (int*)smem;
    int* cnt = S;            // 512
    int* idg = S + 512;      // 2048
    int* cur = S + 2560;     // 2000
    for (int i = tid; i < 512;  i += 512) cnt[i] = 0;
    for (int i = tid; i < 2048; i += 512) idg[i] = 0;
    __syncthreads();
    for (int e = tid; e < E_N; e += 512){
      int d = ei[E_N + e], r = et[e];
      atomicAdd(&cnt[d], 1);
      atomicAdd(&idg[r*NN + d], 1);
    }
    __syncthreads();
    for (int off = 1; off < 512; off <<= 1){
      int v = (tid >= off) ? cnt[tid - off] : 0;
      __syncthreads();
      cnt[tid] += v;
      __syncthreads();
    }
    if (tid < NN){
      int o  = tid ? cnt[tid-1] : 0;
      int c1 = o  + idg[tid];
      int c2 = c1 + idg[NN + tid];
      int c3 = c2 + idg[2*NN + tid];
      begr[tid*4+0] = o;  begr[tid*4+1] = c1;
      begr[tid*4+2] = c2; begr[tid*4+3] = c3;
      cur[tid*4+0] = o;  cur[tid*4+1] = c1;
      cur[tid*4+2] = c2; cur[tid*4+3] = c3;
      #pragma unroll
      for (int r = 0; r < 4; r++)
        inv_deg[r*NN+tid] = 1.f / fmaxf((float)idg[r*NN+tid], 1.f);
    }
    if (tid == 0) begr[2000] = E_N;
    __syncthreads();
    for (int e = tid; e < E_N; e += 512){
      int s = ei[e], d = ei[E_N + e], r = et[e];
      int pos = atomicAdd(&cur[d*4 + r], 1);
      e_s[pos] = s;
    }
    return;
  }

  // ---------------- temporal path (identical core to r14) ----------------
  int w = __builtin_amdgcn_readfirstlane(tid >> 6);
  int lane = tid & 63;
  int b  = blockIdx.x >> 3;
  int n0 = (blockIdx.x & 7) << 6;
  int span = (NN - n0 < 64) ? (NN - n0) : 64;

  for (int c = 0; c < 3; c++){
    const float* base = obs + (size_t)(b*3 + c)*25000;
    for (int idx = tid; idx < 3200; idx += 512){
      int n = idx / 50, t = idx % 50;
      int node = n0 + n; if (node > NN-1) node = NN-1;
      OL(n, c*50 + t) = base[node*50 + t];
    }
  }
  __syncthreads();

  float acc[20];
  float mx[3] = {-1e30f, -1e30f, -1e30f};
  if (w < 5){
    int t0 = w * 6;
    float ov[3][26];
    #pragma unroll
    for (int ci = 0; ci < 3; ci++)
      #pragma unroll
      for (int j = 0; j < 26; j++)
        ov[ci][j] = OL(lane, ci*50 + t0 + j);
    float sc1[3], sh1[3];
    #pragma unroll
    for (int ci = 0; ci < 3; ci++){
      float s = mbn1[ci] * rsqrtf(mbn1[9+ci] + EPSV);
      sc1[ci] = s; sh1[ci] = mbn1[3+ci] - mbn1[6+ci]*s;
    }
    #pragma unroll
    for (int o = 0; o < 20; o++) acc[o] = 0.f;
    #pragma unroll
    for (int i = 0; i < 6; i++){
      int tt = t0 + i;
      float mv[3];
      #pragma unroll
      for (int co = 0; co < 3; co++) mv[co] = mc1b[co];
      #pragma unroll
      for (int ci = 0; ci < 3; ci++)
        #pragma unroll
        for (int k = 0; k < 21; k++){
          float v = ov[ci][i + k];
          #pragma unroll
          for (int co = 0; co < 3; co++) mv[co] += v * mc1w[co*63 + ci*21 + k];
        }
      #pragma unroll
      for (int co = 0; co < 3; co++){
        float z = lrelu(mv[co]*sc1[co] + sh1[co]);
        const float* wp = wT_m2 + (co*30 + tt)*20;
        #pragma unroll
        for (int o = 0; o < 20; o++) acc[o] += z * wp[o];
      }
    }
  } else {
    int ws_ = w - 5;
    int t0 = ws_ * 16;
    float ovs[3][18];
    #pragma unroll
    for (int ci = 0; ci < 3; ci++)
      #pragma unroll
      for (int j = 0; j < 18; j++)
        ovs[ci][j] = OL(lane, ci*50 + t0 + j);
    int l0 = ws_ * 17;
    int ln = (50 - l0 < 17) ? (50 - l0) : 17;
    for (int j = 0; j < ln; j++){
      #pragma unroll
      for (int c = 0; c < 3; c++)
        mx[c] = fmaxf(mx[c], OL(lane, c*50 + l0 + j));
    }
    float sc1[3], sh1[3];
    #pragma unroll
    for (int ci = 0; ci < 3; ci++){
      float s = sbn1[ci] * rsqrtf(sbn1[9+ci] + EPSV);
      sc1[ci] = s; sh1[ci] = sbn1[3+ci] - sbn1[6+ci]*s;
    }
    #pragma unroll
    for (int o = 0; o < 20; o++) acc[o] = 0.f;
    #pragma unroll
    for (int i = 0; i < 16; i++){
      int tt = t0 + i;
      float sv[3];
      #pragma unroll
      for (int co = 0; co < 3; co++) sv[co] = sc1b[co];
      #pragma unroll
      for (int ci = 0; ci < 3; ci++)
        #pragma unroll
        for (int k = 0; k < 3; k++){
          float v = ovs[ci][i + k];
          #pragma unroll
          for (int co = 0; co < 3; co++) sv[co] += v * sc1w[co*9 + ci*3 + k];
        }
      #pragma unroll
      for (int co = 0; co < 3; co++){
        float z = lrelu(sv[co]*sc1[co] + sh1[co]);
        const float* wp = wT_s2 + (co*48 + tt)*20;
        #pragma unroll
        for (int o = 0; o < 20; o++) acc[o] += z * wp[o];
      }
    }
  }
  __syncthreads();

  #pragma unroll
  for (int o = 0; o < 20; o++) PB(w, lane, o) = acc[o];
  if (w >= 5){
    #pragma unroll
    for (int c = 0; c < 3; c++) PB(w, lane, 20 + c) = mx[c];
  }
  __syncthreads();

  size_t gx = (size_t)(b*NN + n0)*XSTRIDE;
  for (int idx = tid; idx < 64*20; idx += 512){
    int n = idx / 20, o = idx % 20;
    if (n < span){
      float v = PB(0,n,o) + PB(1,n,o) + PB(2,n,o) + PB(3,n,o) + PB(4,n,o);
      xbuf[gx + (size_t)n*XSTRIDE + 20 + o] = lrelu(bnap(v + mc2b[o], mbn2, o, 20));
    }
  }
  for (int idx = tid; idx < 64*20; idx += 512){
    int n = idx / 20, o = idx % 20;
    if (n < span){
      float v = PB(5,n,o) + PB(6,n,o) + PB(7,n,o);
      xbuf[gx + (size_t)n*XSTRIDE + o] = lrelu(bnap(v + sc2b[o], sbn2, o, 20));
    }
  }
  for (int idx = tid; idx < 64*3; idx += 512){
    int n = idx / 3, c = idx % 3;
    if (n < span){
      float v = fmaxf(fmaxf(PB(5,n,20+c), PB(6,n,20+c)), PB(7,n,20+c));
      xbuf[gx + (size_t)n*XSTRIDE + 40 + c] = lrelu(v);
    }
  }
  #undef OL
  #undef PB
}

// ============ graph15: graph13 + fused logits ============
// Each block owns 64 nodes; after the transform, waves reduce their 3-channel
// logit partials (+ wave 15: x-part and action) in LDS -> o_ws directly.
__global__ __launch_bounds__(1024) void k_graph15(
    const float* __restrict__ xbuf, const float* __restrict__ wTg,
    fp gb, fp gbnp, const float* __restrict__ inv_deg,
    const int* __restrict__ begr, const int* __restrict__ e_s,
    fp action, fp acw, fp acb,
    float* __restrict__ gbuf, float* __restrict__ o_ws)
{
  __shared__ float xin[64][219];
  __shared__ float lred[16][64];
  int p = blockIdx.x;
  int l = ((p & 7) * 63) + (p >> 3);
  if (l >= 500) return;
  int tid = threadIdx.x;
  int w = tid >> 6, lane = tid & 63;
  int g0 = l * 64;

  for (int q = 0; q < 4; q++){
    int nl = (w << 2) + q;
    int g = __builtin_amdgcn_readfirstlane(g0 + nl);
    int b = g / NN;
    int n = g - b * NN;
    const float* xb = xbuf + (size_t)(b * NN) * XSTRIDE;
    float xv = (lane < FF) ? xbuf[(size_t)g*XSTRIDE + lane] : 0.f;
    float ar[4];
    #pragma unroll
    for (int r = 0; r < 4; r++){
      int beg = __builtin_amdgcn_readfirstlane(begr[n*4 + r]);
      int end = __builtin_amdgcn_readfirstlane(begr[n*4 + r + 1]);
      float a0 = 0.f, a1 = 0.f, a2 = 0.f, a3 = 0.f;
      int i = beg;
      for (; i + 4 <= end; i += 4){
        int s0 = e_s[i], s1 = e_s[i+1], s2 = e_s[i+2], s3 = e_s[i+3];
        float v0 = (lane < FF) ? xb[(size_t)s0*XSTRIDE + lane] : 0.f;
        float v1 = (lane < FF) ? xb[(size_t)s1*XSTRIDE + lane] : 0.f;
        float v2 = (lane < FF) ? xb[(size_t)s2*XSTRIDE + lane] : 0.f;
        float v3 = (lane < FF) ? xb[(size_t)s3*XSTRIDE + lane] : 0.f;
        a0 += v0; a1 += v1; a2 += v2; a3 += v3;
      }
      for (; i < end; i++){
        int s = e_s[i];
        a0 += (lane < FF) ? xb[(size_t)s*XSTRIDE + lane] : 0.f;
      }
      ar[r] = ((a0 + a1) + (a2 + a3)) * inv_deg[r*NN + n];
    }
    if (lane < FF){
      xin[nl][lane]       = xv;
      xin[nl][ 43 + lane] = ar[0];
      xin[nl][ 86 + lane] = ar[1];
      xin[nl][129 + lane] = ar[2];
      xin[nl][172 + lane] = ar[3];
    }
  }
  __syncthreads();

  int c0 = __builtin_amdgcn_readfirstlane(w * 3);
  int g = g0 + lane;
  float acc[3];
  #pragma unroll
  for (int j = 0; j < 3; j++) acc[j] = (c0 + j < FF) ? gb[c0+j] : 0.f;
  for (int f = 0; f < 215; f++){
    float v = xin[lane][f];
    const float* wp = wTg + f*43 + c0;
    #pragma unroll
    for (int j = 0; j < 3; j++) acc[j] += v * wp[j];
  }
  float lp = 0.f;
  #pragma unroll
  for (int j = 0; j < 3; j++){
    int c = c0 + j;
    if (c < FF){
      float gv = lrelu(bnap(acc[j], gbnp, c, FF));
      gbuf[(size_t)g*XSTRIDE + c] = gv;
      lp += gv * acw[1 + FF + c];
    }
  }
  if (w == 15){           // idle in channel space (c0=45): compute x-part
    int b = g / NN, n = g - b * NN;
    float xp = acb[0] + action[b*(PP+1) + 1 + n] * acw[0];
    #pragma unroll 2
    for (int c = 0; c < FF; c++) xp += xin[lane][c] * acw[1 + c];
    lp = xp;
  }
  lred[w][lane] = lp;
  __syncthreads();
  if (tid < 64){
    float t = 0.f;
    #pragma unroll
    for (int w2 = 0; w2 < 16; w2++) t += lred[w2][tid];
    int g2 = g0 + tid;
    int b = g2 / NN, n = g2 - b * NN;
    o_ws[b*(PP+1) + 1 + n] = t;
  }
}

// ============ fcall (unchanged from r14) ============
__global__ __launch_bounds__(512) void k_fcall(
    const float* __restrict__ o_ws,
    fp aw1, fp ab1, fp aw2, fp ab2, fp aw3, fp ab3,
    float* __restrict__ out)
{
  int b = blockIdx.x;
  int tid = threadIdx.x;
  __shared__ float os[PP+1];
  __shared__ float part[4][HH];
  __shared__ float h1[HH];
  __shared__ float h2[HH];
  __shared__ float red[512];

  if (tid <= PP) os[tid] = o_ws[b*(PP+1) + tid];
  __syncthreads();

  {
    int chunk = tid >> 7, h = tid & 127;
    int k0 = chunk * 125;
    int kn = (chunk == 3) ? 126 : 125;
    float acc = 0.f;
    for (int k = 0; k < kn; k++) acc += os[k0+k] * aw1[(k0+k)*HH + h];
    part[chunk][h] = acc;
  }
  __syncthreads();
  if (tid < HH)
    h1[tid] = fmaxf(ab1[tid] + part[0][tid] + part[1][tid] + part[2][tid] + part[3][tid], 0.f);
  __syncthreads();
  if (tid < HH){
    float acc = ab2[tid];
    #pragma unroll 4
    for (int k = 0; k < HH; k++) acc += h1[k] * aw2[k*HH + tid];
    h2[tid] = fmaxf(acc, 0.f);
  }
  __syncthreads();

  float val = -1e30f;
  if (tid <= PP){
    float acc = ab3[tid];
    #pragma unroll 4
    for (int k = 0; k < HH; k++) acc += h2[k] * aw3[k*(PP+1) + tid];
    val = acc;
  }
  red[tid] = val;
  __syncthreads();
  for (int s = 256; s > 0; s >>= 1){
    if (tid < s) red[tid] = fmaxf(red[tid], red[tid + s]);
    __syncthreads();
  }
  float mxv = red[0];
  __syncthreads();
  float e = (tid <= PP) ? expf(val - mxv) : 0.f;
  red[tid] = e;
  __syncthreads();
  for (int s = 256; s > 0; s >>= 1){
    if (tid < s) red[tid] += red[tid + s];
    __syncthreads();
  }
  float sum = red[0];
  if (tid <= PP) out[b*(PP+1) + tid] = e / sum;
}

extern "C" void kernel_launch(void* const* d_in, const int* in_sizes, int n_in,
                              void* d_out, int out_size, void* d_ws, size_t ws_size,
                              hipStream_t stream)
{
  fp obs    = (fp)d_in[0];
  fp action = (fp)d_in[1];
  const int* ei  = (const int*)d_in[2];
  const int* et  = (const int*)d_in[3];
  fp sc1w=(fp)d_in[5],  sc1b=(fp)d_in[6],  sbn1=(fp)d_in[7];
  fp sc2w=(fp)d_in[8],  sc2b=(fp)d_in[9],  sbn2=(fp)d_in[10];
  fp mc1w=(fp)d_in[11], mc1b=(fp)d_in[12], mbn1=(fp)d_in[13];
  fp mc2w=(fp)d_in[14], mc2b=(fp)d_in[15], mbn2=(fp)d_in[16];
  fp gwroot=(fp)d_in[17], gwrel=(fp)d_in[18], gb=(fp)d_in[19], gbnp=(fp)d_in[20];
  fp acw=(fp)d_in[21], acb=(fp)d_in[22];
  fp aw1=(fp)d_in[23], ab1=(fp)d_in[24];
  fp aw2=(fp)d_in[25], ab2=(fp)d_in[26];
  fp aw3=(fp)d_in[27], ab3=(fp)d_in[28];

  float* xbuf   = (float*)d_ws;              // 1,536,000
  float* gbuf   = xbuf + 1536000;            // 1,536,000
  float* wT_s2  = gbuf + 1536000;            // 2880
  float* wT_m2  = wT_s2 + 2880;              // 1800
  float* wTg    = wT_m2 + 1800;              // 9312
  float* invdeg = wTg + 9312;                // 2000
  float* o_ws   = invdeg + 2000;             // 32064
  int*   ip     = (int*)(o_ws + 32064);
  int* begr = ip;               // 2001
  int* e_s  = ip + 2001;        // 16000

  float* out = (float*)d_out;

  hipLaunchKernelGGL(k_prep15, dim3(8), dim3(1024), 0, stream,
    sc2w, mc2w, gwroot, gwrel, wT_s2, wT_m2, wTg, o_ws);
  hipLaunchKernelGGL(k_tempo15, dim3(513), dim3(512), 0, stream,
    obs, sc1w, sc1b, sbn1, sc2b, sbn2,
    mc1w, mc1b, mbn1, mc2b, mbn2, wT_s2, wT_m2, xbuf,
    ei, et, begr, e_s, invdeg);
  hipLaunchKernelGGL(k_graph15, dim3(504), dim3(1024), 0, stream,
    xbuf, wTg, gb, gbnp, invdeg, begr, e_s, action, acw, acb, gbuf, o_ws);
  hipLaunchKernelGGL(k_fcall, dim3(BB), dim3(512), 0, stream,
    o_ws, aw1, ab1, aw2, ab2, aw3, ab3, out);
}